// Round 17
// baseline (589.923 us; speedup 1.0000x reference)
//
#include <hip/hip_runtime.h>
#include <stdint.h>

typedef unsigned short u16;
typedef float f32x4 __attribute__((ext_vector_type(4)));
typedef short s16x8 __attribute__((ext_vector_type(8)));
typedef short s16x4 __attribute__((ext_vector_type(4)));
typedef int   i32x4 __attribute__((ext_vector_type(4)));

constexpr int B  = 8;
constexpr int S  = 1024;
constexpr int DM = 1024;
constexpr int H  = 16;
constexpr int M  = B * S;          // 8192 rows
constexpr float NEGINF = -1e9f;

__device__ __forceinline__ u16 f2bf(float f) {
    union { float f; uint32_t u; } v; v.f = f;
    uint32_t u = v.u;
    uint32_t r = 0x7FFFu + ((u >> 16) & 1u);   // round-to-nearest-even
    return (u16)((u + r) >> 16);
}
__device__ __forceinline__ float bf2f(u16 h) {
    union { uint32_t u; float f; } v; v.u = ((uint32_t)h) << 16; return v.f;
}

// async global->LDS 16B (m97 form): LDS dest = wave-uniform base + lane*16
__device__ __forceinline__ void gload16(const u16* g, u16* l) {
    __builtin_amdgcn_global_load_lds(
        (const __attribute__((address_space(1))) unsigned int*)g,
        (__attribute__((address_space(3))) unsigned int*)l, 16, 0, 0);
}

// ---------------- fp32 -> bf16, all three inputs in one launch ----------------
__global__ void cvt_all(const float* __restrict__ q, const float* __restrict__ k,
                        const float* __restrict__ v,
                        u16* __restrict__ xq, u16* __restrict__ xk, u16* __restrict__ xv) {
    const float* in; u16* out;
    if (blockIdx.y == 0)      { in = q; out = xq; }
    else if (blockIdx.y == 1) { in = k; out = xk; }
    else                      { in = v; out = xv; }
    int i = (blockIdx.x * 256 + threadIdx.x) * 4;
    float4 val = *(const float4*)(in + i);
    ushort4 o;
    o.x = f2bf(val.x); o.y = f2bf(val.y); o.z = f2bf(val.z); o.w = f2bf(val.w);
    *(ushort4*)(out + i) = o;
}

// ---------------- W[k][n] fp32 -> Wt[n][k] bf16, all four weights ----------------
__global__ void transpose_all(const float* __restrict__ w0, const float* __restrict__ w1,
                              const float* __restrict__ w2, const float* __restrict__ w3,
                              u16* __restrict__ o0, u16* __restrict__ o1,
                              u16* __restrict__ o2, u16* __restrict__ o3) {
    const float* W; u16* Wt;
    switch (blockIdx.z) {
        case 0:  W = w0; Wt = o0; break;
        case 1:  W = w1; Wt = o1; break;
        case 2:  W = w2; Wt = o2; break;
        default: W = w3; Wt = o3; break;
    }
    __shared__ float tile[32][33];
    int n0 = blockIdx.x * 32, k0 = blockIdx.y * 32;
    int tx = threadIdx.x & 31, ty = threadIdx.x >> 5;   // 32 x 8
#pragma unroll
    for (int r = 0; r < 4; ++r)
        tile[ty + r*8][tx] = W[(size_t)(k0 + ty + r*8) * DM + n0 + tx];
    __syncthreads();
#pragma unroll
    for (int r = 0; r < 4; ++r)
        Wt[(size_t)(n0 + ty + r*8) * DM + k0 + tx] = f2bf(tile[tx][ty + r*8]);
}

// ---------------- GEMM: C[M x 1024] = A[M x 1024] * Bt[1024 x 1024]^T ----------------
template<int EPI>
__global__ __launch_bounds__(256, 2)
void gemm_bt(const u16* __restrict__ A, const u16* __restrict__ Bt,
             void* __restrict__ Cv, const float* __restrict__ resid)
{
    __shared__ u16 As[128 * 32];
    __shared__ u16 Bs[128 * 32];
    const int m0 = blockIdx.x * 128;
    const int n0 = blockIdx.y * 128;
    const int t = threadIdx.x;
    const int lane = t & 63;
    const int wid = t >> 6;
    const int wm = (wid >> 1) * 64;
    const int wn = (wid & 1) * 64;
    const int lr = lane & 15;
    const int lg = lane >> 4;

    const u16* Ag = A  + (size_t)(m0 + (t >> 2)) * 1024 + (t & 3) * 8;
    const u16* Bg = Bt + (size_t)(n0 + (t >> 2)) * 1024 + (t & 3) * 8;
    u16* Al = As + t * 8;
    u16* Bl = Bs + t * 8;

    f32x4 acc[4][4] = {};

    for (int kt = 0; kt < 32; ++kt) {
        const int ko = kt * 32;
        __syncthreads();
        gload16(Ag + ko,            Al);
        gload16(Ag + 64*1024 + ko,  Al + 64*32);
        gload16(Bg + ko,            Bl);
        gload16(Bg + 64*1024 + ko,  Bl + 64*32);
        __syncthreads();
        s16x8 af[4], bfr[4];
#pragma unroll
        for (int m = 0; m < 4; ++m)
            af[m] = *(const s16x8*)(As + (wm + m*16 + lr) * 32 + lg * 8);
#pragma unroll
        for (int n = 0; n < 4; ++n)
            bfr[n] = *(const s16x8*)(Bs + (wn + n*16 + lr) * 32 + lg * 8);
#pragma unroll
        for (int m = 0; m < 4; ++m)
#pragma unroll
            for (int n = 0; n < 4; ++n)
                acc[m][n] = __builtin_amdgcn_mfma_f32_16x16x32_bf16(af[m], bfr[n], acc[m][n], 0, 0, 0);
    }

#pragma unroll
    for (int m = 0; m < 4; ++m) {
#pragma unroll
        for (int n = 0; n < 4; ++n) {
            const int rg0 = m0 + wm + m*16 + lg*4;   // D row = (lane>>4)*4 + reg
            const int cg  = n0 + wn + n*16 + lr;     // D col = lane&15
            if constexpr (EPI == 0) {
                u16* C = (u16*)Cv;
#pragma unroll
                for (int r = 0; r < 4; ++r)
                    C[(size_t)(rg0 + r) * 1024 + cg] = f2bf(acc[m][n][r]);
            } else if constexpr (EPI == 1) {
                u16* C = (u16*)Cv;
                const int bb = rg0 >> 10;
                const int s0 = rg0 & 1023;
                const int hh = cg >> 6;
                const int dd = cg & 63;
                ushort4 pk;
                pk.x = f2bf(acc[m][n][0]); pk.y = f2bf(acc[m][n][1]);
                pk.z = f2bf(acc[m][n][2]); pk.w = f2bf(acc[m][n][3]);
                *(ushort4*)(C + (size_t)((bb*16 + hh)*64 + dd) * 1024 + s0) = pk;
            } else {
                float* C = (float*)Cv;
#pragma unroll
                for (int r = 0; r < 4; ++r) {
                    size_t idx = (size_t)(rg0 + r) * 1024 + cg;
                    C[idx] = acc[m][n][r] + resid[idx];
                }
            }
        }
    }
}

// ---------------- kernel A: scores + softmax -> normalized attn fp32 ----------------
// R16's verified QK phase (asm-batched loads, counted vmcnt) minus PV/Plds.
__global__ __launch_bounds__(256, 2)
void attn_scores(const u16* __restrict__ Qp, const u16* __restrict__ Kp,
                 const void* __restrict__ maskp, float* __restrict__ attn)
{
    const int i  = blockIdx.x;
    const int qt = (i >> 3) & 63;
    const int g  = ((i >> 9) << 3) | (i & 7);   // g%8 == i%8 -> same XCD per (b,h)
    const int h  = g & 15;
    const int b  = g >> 4;
    const int q0 = qt * 16;

    const int t = threadIdx.x;
    const int lane = t & 63;
    const int w = t >> 6;
    const int lr = lane & 15;
    const int lg = lane >> 4;

    __shared__ float redB[4][16];

    uint32_t orv = 0;
    const uint32_t* mw = (const uint32_t*)maskp;
#pragma unroll
    for (int ii = 0; ii < 64; ++ii) orv |= mw[ii];
    const bool mask_bytes = (orv > 1u);

    const u16* qb = Qp + (size_t)(b*S + q0 + lr) * DM + h*64 + lg*8;
    s16x8 qf0 = *(const s16x8*)(qb);
    s16x8 qf1 = *(const s16x8*)(qb + 32);

    const size_t mrow = (size_t)b * S * S + (size_t)(q0 + lr) * S;

    i32x4 kf0s[2][4], kf1s[2][4], mis[2][4];
    int   mbs[2][4];
    s16x4 paf[16];
    float hs = 0.f;

#define QK_ISSUE(st, nb_) do {                                                      \
    _Pragma("unroll")                                                               \
    for (int j = 0; j < 4; ++j) {                                                   \
        const u16* kb_ = Kp + (size_t)(b*S + w*256 + (nb_)*64 + j*16 + lr) * DM     \
                            + h*64 + lg*8;                                          \
        asm volatile("global_load_dwordx4 %0, %2, off\n\t"                          \
                     "global_load_dwordx4 %1, %2, off offset:64"                    \
                     : "=v"(kf0s[st][j]), "=v"(kf1s[st][j]) : "v"(kb_));            \
        const size_t off_ = mrow + w*256 + (nb_)*64 + j*16 + lg*4;                  \
        if (mask_bytes) {                                                           \
            asm volatile("global_load_dword %0, %1, off"                            \
                         : "=v"(mbs[st][j]) : "v"((const uint8_t*)maskp + off_));   \
        } else {                                                                    \
            asm volatile("global_load_dwordx4 %0, %1, off"                          \
                         : "=v"(mis[st][j]) : "v"((const int*)maskp + off_));       \
        }                                                                           \
    }                                                                               \
} while (0)

#define QK_COMPUTE(st, nb_) do {                                                    \
    _Pragma("unroll")                                                               \
    for (int j = 0; j < 4; ++j) {                                                   \
        const int nk_ = (nb_)*4 + j;                                                \
        s16x8 kf0 = *(const s16x8*)&kf0s[st][j];                                    \
        s16x8 kf1 = *(const s16x8*)&kf1s[st][j];                                    \
        int m0_, m1_, m2_, m3_;                                                     \
        if (mask_bytes) {                                                           \
            int mm = mbs[st][j];                                                    \
            m0_ = mm & 255; m1_ = (mm >> 8) & 255;                                  \
            m2_ = (mm >> 16) & 255; m3_ = ((unsigned)mm) >> 24;                     \
        } else {                                                                    \
            m0_ = mis[st][j][0]; m1_ = mis[st][j][1];                               \
            m2_ = mis[st][j][2]; m3_ = mis[st][j][3];                               \
        }                                                                           \
        f32x4 cc = {};                                                              \
        cc = __builtin_amdgcn_mfma_f32_16x16x32_bf16(kf0, qf0, cc, 0, 0, 0);        \
        cc = __builtin_amdgcn_mfma_f32_16x16x32_bf16(kf1, qf1, cc, 0, 0, 0);        \
        cc[0] = __expf(m0_ ? NEGINF : cc[0] * 0.125f);                              \
        cc[1] = __expf(m1_ ? NEGINF : cc[1] * 0.125f);                              \
        cc[2] = __expf(m2_ ? NEGINF : cc[2] * 0.125f);                              \
        cc[3] = __expf(m3_ ? NEGINF : cc[3] * 0.125f);                              \
        hs += cc[0] + cc[1] + cc[2] + cc[3];                                        \
        s16x4 pa;                                                                   \
        pa[0] = (short)f2bf(cc[0]); pa[1] = (short)f2bf(cc[1]);                     \
        pa[2] = (short)f2bf(cc[2]); pa[3] = (short)f2bf(cc[3]);                     \
        paf[nk_] = pa;                                                              \
    }                                                                               \
} while (0)

    QK_ISSUE(0, 0);
    QK_ISSUE(1, 1);
    asm volatile("s_waitcnt vmcnt(12)");
    __builtin_amdgcn_sched_barrier(0);
    QK_COMPUTE(0, 0);
    QK_ISSUE(0, 2);
    asm volatile("s_waitcnt vmcnt(12)");
    __builtin_amdgcn_sched_barrier(0);
    QK_COMPUTE(1, 1);
    QK_ISSUE(1, 3);
    asm volatile("s_waitcnt vmcnt(12)");
    __builtin_amdgcn_sched_barrier(0);
    QK_COMPUTE(0, 2);
    asm volatile("s_waitcnt vmcnt(0)");
    __builtin_amdgcn_sched_barrier(0);
    QK_COMPUTE(1, 3);
#undef QK_ISSUE
#undef QK_COMPUTE

    hs += __shfl_xor(hs, 16, 64);
    hs += __shfl_xor(hs, 32, 64);
    if (lane < 16) redB[w][lr] = hs;
    __syncthreads();
    const float tot = redB[0][lr] + redB[1][lr] + redB[2][lr] + redB[3][lr];
    const float inv  = tot > 0.f ? 1.0f / tot : 0.f;
    const float fill = tot > 0.f ? 0.f : (1.0f / 1024.0f);

    float* arow = attn + (size_t)(b*H + h) * S * S + (size_t)(q0 + lr) * S + w*256 + lg*4;
#pragma unroll
    for (int nk = 0; nk < 16; ++nk) {
        float4 st;
        st.x = fmaf(bf2f((u16)paf[nk][0]), inv, fill);
        st.y = fmaf(bf2f((u16)paf[nk][1]), inv, fill);
        st.z = fmaf(bf2f((u16)paf[nk][2]), inv, fill);
        st.w = fmaf(bf2f((u16)paf[nk][3]), inv, fill);
        *(float4*)(arow + nk*16) = st;
    }
}

// ---------------- kernel B: ctx = attn @ V as a DMA-fed GEMM (m97 structure) ----------------
// Per head g: C[128q x 64d] = P[128 x 1024] * V^T. Grid 1024, XCD-swizzled
// (i bits [9:6]=gHi, [5:3]=qt, [2:0]=gLo). 4 waves, wave w owns 32q x 64d.
// BK=64, double-buffered: A = attn fp32 [128][64] (32KB), B = Vt bf16 [64][64]
// (8KB), both staged by global_load_lds (no VGPR load queue — escapes the
// per-wave outstanding-load wall R16 proved). Swizzle per rule #21: linear LDS
// dest, PRE-SWIZZLED global source, swizzled read addr.
//   A: 32B-chunk XOR (row&7)  -> 4-way read conflicts (1.58x, acceptable)
//   B: 16B-slot  XOR (row&7)  -> 2-way (free)
// Loop: prefetch(k+1) -> compute(k) -> barrier (DMA latency hides under MFMA+cvt).
__global__ __launch_bounds__(256, 2)
void attn_pv_gemm(const float* __restrict__ attn, const u16* __restrict__ Vt,
                  u16* __restrict__ ctx)
{
    __shared__ float Abuf[2][128 * 64];   // 2 x 32KB
    __shared__ u16   Vbuf[2][64 * 64];    // 2 x 8KB
    const int i  = blockIdx.x;
    const int qt = (i >> 3) & 7;
    const int g  = ((i >> 6) << 3) | (i & 7);
    const int h  = g & 15;
    const int b  = g >> 4;
    const int q0 = qt * 128;

    const int t = threadIdx.x;
    const int lane = t & 63;
    const int w = t >> 6;
    const int lr = lane & 15;
    const int lg = lane >> 4;

    const float* abase = attn + (size_t)(b*H + h) * S * S + (size_t)q0 * S;
    const u16*   vbase = Vt + (size_t)g * 64 * S;

#define PSTAGE(bi, kk) do {                                                         \
    const int k0_ = (kk) * 64;                                                      \
    _Pragma("unroll")                                                               \
    for (int j = 0; j < 8; ++j) {                                                   \
        const int s_ = j*256 + t;              /* 16B slot in [0,2048) */           \
        const int r_ = s_ >> 4;                /* q-local row */                    \
        const int p_ = s_ & 15;                /* phys 16B slot in row */           \
        const int l_ = p_ ^ ((r_ & 7) << 1);   /* logical slot (32B-chunk XOR) */   \
        gload16((const u16*)(abase + (size_t)r_ * S + k0_ + l_*4),                  \
                (u16*)&Abuf[bi][s_ * 4]);                                           \
    }                                                                               \
    _Pragma("unroll")                                                               \
    for (int j = 0; j < 2; ++j) {                                                   \
        const int s_ = j*256 + t;              /* [0,512) */                        \
        const int r_ = s_ >> 3;                /* d row */                          \
        const int p_ = s_ & 7;                                                      \
        const int l_ = p_ ^ (r_ & 7);                                               \
        gload16(vbase + (size_t)r_ * S + k0_ + l_*8, &Vbuf[bi][s_ * 8]);            \
    }                                                                               \
} while (0)

    f32x4 acc[2][4] = {};

    PSTAGE(0, 0);
    __syncthreads();                      // drains vmcnt -> chunk 0 ready

    for (int k = 0; k < 16; ++k) {
        const int cur = k & 1;
        if (k < 15) PSTAGE(cur ^ 1, k + 1);
        // compute on buf[cur]
#pragma unroll
        for (int ks = 0; ks < 2; ++ks) {
            s16x8 af[2];
#pragma unroll
            for (int fq = 0; fq < 2; ++fq) {
                const int row = w*32 + fq*16 + lr;
                const int ch  = (ks*4 + lg) ^ (lr & 7);    // 32B chunk (swizzled)
                const float* ap = &Abuf[cur][row*64 + ch*8];
                float4 a0 = *(const float4*)(ap);
                float4 a1 = *(const float4*)(ap + 4);
                s16x8 v;
                v[0] = (short)f2bf(a0.x); v[1] = (short)f2bf(a0.y);
                v[2] = (short)f2bf(a0.z); v[3] = (short)f2bf(a0.w);
                v[4] = (short)f2bf(a1.x); v[5] = (short)f2bf(a1.y);
                v[6] = (short)f2bf(a1.z); v[7] = (short)f2bf(a1.w);
                af[fq] = v;
            }
#pragma unroll
            for (int nd = 0; nd < 4; ++nd) {
                const int row = nd*16 + lr;
                const int sl  = (ks*4 + lg) ^ (lr & 7);    // 16B slot (swizzled)
                s16x8 vf = *(const s16x8*)&Vbuf[cur][row*64 + sl*8];
#pragma unroll
                for (int fq = 0; fq < 2; ++fq)
                    acc[fq][nd] = __builtin_amdgcn_mfma_f32_16x16x32_bf16(af[fq], vf, acc[fq][nd], 0, 0, 0);
            }
        }
        __syncthreads();                  // drains k+1 DMA; protects buffer reuse
    }
#undef PSTAGE

    // D[row=lg*4+r -> q within frag fq][col=lr -> d within frag nd]
#pragma unroll
    for (int fq = 0; fq < 2; ++fq)
#pragma unroll
        for (int nd = 0; nd < 4; ++nd)
#pragma unroll
            for (int r = 0; r < 4; ++r)
                ctx[(size_t)(b*S + q0 + w*32 + fq*16 + lg*4 + r) * DM + h*64 + nd*16 + lr]
                    = f2bf(acc[fq][nd][r]);
}

// ---------------- LayerNorm over rows of 1024 ----------------
__global__ __launch_bounds__(256)
void layernorm(const float* __restrict__ x, const float* __restrict__ gamma,
               const float* __restrict__ beta, float* __restrict__ out)
{
    const int row = blockIdx.x;
    const int t = threadIdx.x;
    const float* xr = x + (size_t)row * DM;
    float4 v = *(const float4*)(xr + t*4);
    float s  = v.x + v.y + v.z + v.w;
    float s2 = v.x*v.x + v.y*v.y + v.z*v.z + v.w*v.w;
#pragma unroll
    for (int d = 1; d < 64; d <<= 1) {
        s  += __shfl_xor(s,  d, 64);
        s2 += __shfl_xor(s2, d, 64);
    }
    __shared__ float ls[4], ls2[4];
    if ((t & 63) == 0) { ls[t >> 6] = s; ls2[t >> 6] = s2; }
    __syncthreads();
    s  = ls[0] + ls[1] + ls[2] + ls[3];
    s2 = ls2[0] + ls2[1] + ls2[2] + ls2[3];
    const float mu  = s * (1.0f / DM);
    const float var = s2 * (1.0f / DM) - mu * mu;
    const float rs  = rsqrtf(var + 1e-5f);
    float4 g  = *(const float4*)(gamma + t*4);
    float4 bb = *(const float4*)(beta  + t*4);
    float4 o;
    o.x = (v.x - mu) * rs * g.x + bb.x;
    o.y = (v.y - mu) * rs * g.y + bb.y;
    o.z = (v.z - mu) * rs * g.z + bb.z;
    o.w = (v.w - mu) * rs * g.w + bb.w;
    *(float4*)(out + (size_t)row * DM + t*4) = o;
}

extern "C" void kernel_launch(void* const* d_in, const int* in_sizes, int n_in,
                              void* d_out, int out_size, void* d_ws, size_t ws_size,
                              hipStream_t stream) {
    const float* Qin  = (const float*)d_in[0];
    const float* Kin  = (const float*)d_in[1];
    const float* Vin  = (const float*)d_in[2];
    const void*  mask = d_in[3];
    const float* Wq   = (const float*)d_in[4];
    const float* Wk   = (const float*)d_in[5];
    const float* Wv   = (const float*)d_in[6];
    const float* Wfc  = (const float*)d_in[7];
    const float* gam  = (const float*)d_in[8];
    const float* bet  = (const float*)d_in[9];

    float* out  = (float*)d_out;
    float* attn = (float*)d_out + (size_t)M * DM;

    char* ws = (char*)d_ws;
    constexpr size_t SZ_X = (size_t)M * DM * 2;    // 16 MiB
    constexpr size_t SZ_W = (size_t)DM * DM * 2;   // 2 MiB
    u16* Xq  = (u16*)(ws);
    u16* Xk  = (u16*)(ws + SZ_X);
    u16* Xv  = (u16*)(ws + 2*SZ_X);
    u16* WqT = (u16*)(ws + 3*SZ_X);
    u16* WkT = (u16*)(ws + 3*SZ_X + SZ_W);
    u16* WvT = (u16*)(ws + 3*SZ_X + 2*SZ_W);
    u16* WfT = (u16*)(ws + 3*SZ_X + 3*SZ_W);
    u16* Qp  = (u16*)(ws + 3*SZ_X + 4*SZ_W);
    u16* Kp  = (u16*)(ws + 4*SZ_X + 4*SZ_W);
    u16* Vt  = (u16*)(ws + 5*SZ_X + 4*SZ_W);
    // aliases onto dead buffers:
    float* preLN = (float*)(ws);               // 32 MiB over Xq+Xk (dead after projections)
    u16*   Ctx   = (u16*)(ws + 2*SZ_X);        // 16 MiB over Xv   (dead after V projection)

    dim3 blk(256);
    cvt_all<<<dim3(M * DM / 1024, 3), blk, 0, stream>>>(Qin, Kin, Vin, Xq, Xk, Xv);
    transpose_all<<<dim3(32, 32, 4), blk, 0, stream>>>(Wq, Wk, Wv, Wfc, WqT, WkT, WvT, WfT);

    gemm_bt<0><<<dim3(64, 8), blk, 0, stream>>>(Xq, WqT, Qp, nullptr);
    gemm_bt<0><<<dim3(64, 8), blk, 0, stream>>>(Xk, WkT, Kp, nullptr);
    gemm_bt<1><<<dim3(64, 8), blk, 0, stream>>>(Xv, WvT, Vt, nullptr);

    attn_scores<<<dim3(8192), blk, 0, stream>>>(Qp, Kp, mask, attn);
    attn_pv_gemm<<<dim3(1024), blk, 0, stream>>>(attn, Vt, Ctx);

    gemm_bt<2><<<dim3(64, 8), blk, 0, stream>>>(Ctx, WfT, preLN, Qin);
    layernorm<<<dim3(M), blk, 0, stream>>>(preLN, gam, bet, out);
}

// Round 18
// 566.122 us; speedup vs baseline: 1.0420x; 1.0420x over previous
//
#include <hip/hip_runtime.h>
#include <stdint.h>

typedef unsigned short u16;
typedef float f32x4 __attribute__((ext_vector_type(4)));
typedef short s16x8 __attribute__((ext_vector_type(8)));
typedef short s16x4 __attribute__((ext_vector_type(4)));

constexpr int B  = 8;
constexpr int S  = 1024;
constexpr int DM = 1024;
constexpr int H  = 16;
constexpr int M  = B * S;          // 8192 rows
constexpr float NEGINF = -1e9f;

__device__ __forceinline__ u16 f2bf(float f) {
    union { float f; uint32_t u; } v; v.f = f;
    uint32_t u = v.u;
    uint32_t r = 0x7FFFu + ((u >> 16) & 1u);   // round-to-nearest-even
    return (u16)((u + r) >> 16);
}
__device__ __forceinline__ float bf2f(u16 h) {
    union { uint32_t u; float f; } v; v.u = ((uint32_t)h) << 16; return v.f;
}

// async global->LDS 16B (m97 form): LDS dest = wave-uniform base + lane*16
__device__ __forceinline__ void gload16(const u16* g, u16* l) {
    __builtin_amdgcn_global_load_lds(
        (const __attribute__((address_space(1))) unsigned int*)g,
        (__attribute__((address_space(3))) unsigned int*)l, 16, 0, 0);
}

// ---------------- fp32 -> bf16, all three inputs in one launch ----------------
__global__ void cvt_all(const float* __restrict__ q, const float* __restrict__ k,
                        const float* __restrict__ v,
                        u16* __restrict__ xq, u16* __restrict__ xk, u16* __restrict__ xv) {
    const float* in; u16* out;
    if (blockIdx.y == 0)      { in = q; out = xq; }
    else if (blockIdx.y == 1) { in = k; out = xk; }
    else                      { in = v; out = xv; }
    int i = (blockIdx.x * 256 + threadIdx.x) * 4;
    float4 val = *(const float4*)(in + i);
    ushort4 o;
    o.x = f2bf(val.x); o.y = f2bf(val.y); o.z = f2bf(val.z); o.w = f2bf(val.w);
    *(ushort4*)(out + i) = o;
}

// ---------------- W[k][n] fp32 -> Wt[n][k] bf16, all four weights ----------------
__global__ void transpose_all(const float* __restrict__ w0, const float* __restrict__ w1,
                              const float* __restrict__ w2, const float* __restrict__ w3,
                              u16* __restrict__ o0, u16* __restrict__ o1,
                              u16* __restrict__ o2, u16* __restrict__ o3) {
    const float* W; u16* Wt;
    switch (blockIdx.z) {
        case 0:  W = w0; Wt = o0; break;
        case 1:  W = w1; Wt = o1; break;
        case 2:  W = w2; Wt = o2; break;
        default: W = w3; Wt = o3; break;
    }
    __shared__ float tile[32][33];
    int n0 = blockIdx.x * 32, k0 = blockIdx.y * 32;
    int tx = threadIdx.x & 31, ty = threadIdx.x >> 5;   // 32 x 8
#pragma unroll
    for (int r = 0; r < 4; ++r)
        tile[ty + r*8][tx] = W[(size_t)(k0 + ty + r*8) * DM + n0 + tx];
    __syncthreads();
#pragma unroll
    for (int r = 0; r < 4; ++r)
        Wt[(size_t)(n0 + ty + r*8) * DM + k0 + tx] = f2bf(tile[tx][ty + r*8]);
}

// ---------------- GEMM: C[M x 1024] = A[M x 1024] * Bt[1024 x 1024]^T ----------------
// m97 structure: 128x128 tile, BK=32, global_load_lds width=16, linear LDS.
// Grid (m,n) = (x,y): same-m blocks share the A-band and the same id%8 -> same XCD.
// EPI 0: C bf16 row-major.  EPI 1: V transposed -> Vt[(b*16+h)*64+d][s].  EPI 2: fp32 + resid.
template<int EPI>
__global__ __launch_bounds__(256, 2)
void gemm_bt(const u16* __restrict__ A, const u16* __restrict__ Bt,
             void* __restrict__ Cv, const float* __restrict__ resid)
{
    __shared__ u16 As[128 * 32];
    __shared__ u16 Bs[128 * 32];
    const int m0 = blockIdx.x * 128;
    const int n0 = blockIdx.y * 128;
    const int t = threadIdx.x;
    const int lane = t & 63;
    const int wid = t >> 6;
    const int wm = (wid >> 1) * 64;
    const int wn = (wid & 1) * 64;
    const int lr = lane & 15;
    const int lg = lane >> 4;

    const u16* Ag = A  + (size_t)(m0 + (t >> 2)) * 1024 + (t & 3) * 8;
    const u16* Bg = Bt + (size_t)(n0 + (t >> 2)) * 1024 + (t & 3) * 8;
    u16* Al = As + t * 8;
    u16* Bl = Bs + t * 8;

    f32x4 acc[4][4] = {};

    for (int kt = 0; kt < 32; ++kt) {
        const int ko = kt * 32;
        __syncthreads();
        gload16(Ag + ko,            Al);
        gload16(Ag + 64*1024 + ko,  Al + 64*32);
        gload16(Bg + ko,            Bl);
        gload16(Bg + 64*1024 + ko,  Bl + 64*32);
        __syncthreads();
        s16x8 af[4], bfr[4];
#pragma unroll
        for (int m = 0; m < 4; ++m)
            af[m] = *(const s16x8*)(As + (wm + m*16 + lr) * 32 + lg * 8);
#pragma unroll
        for (int n = 0; n < 4; ++n)
            bfr[n] = *(const s16x8*)(Bs + (wn + n*16 + lr) * 32 + lg * 8);
#pragma unroll
        for (int m = 0; m < 4; ++m)
#pragma unroll
            for (int n = 0; n < 4; ++n)
                acc[m][n] = __builtin_amdgcn_mfma_f32_16x16x32_bf16(af[m], bfr[n], acc[m][n], 0, 0, 0);
    }

#pragma unroll
    for (int m = 0; m < 4; ++m) {
#pragma unroll
        for (int n = 0; n < 4; ++n) {
            const int rg0 = m0 + wm + m*16 + lg*4;   // D row = (lane>>4)*4 + reg
            const int cg  = n0 + wn + n*16 + lr;     // D col = lane&15
            if constexpr (EPI == 0) {
                u16* C = (u16*)Cv;
#pragma unroll
                for (int r = 0; r < 4; ++r)
                    C[(size_t)(rg0 + r) * 1024 + cg] = f2bf(acc[m][n][r]);
            } else if constexpr (EPI == 1) {
                u16* C = (u16*)Cv;
                const int bb = rg0 >> 10;
                const int s0 = rg0 & 1023;
                const int hh = cg >> 6;
                const int dd = cg & 63;
                ushort4 pk;
                pk.x = f2bf(acc[m][n][0]); pk.y = f2bf(acc[m][n][1]);
                pk.z = f2bf(acc[m][n][2]); pk.w = f2bf(acc[m][n][3]);
                *(ushort4*)(C + (size_t)((bb*16 + hh)*64 + dd) * 1024 + s0) = pk;
            } else {
                float* C = (float*)Cv;
#pragma unroll
                for (int r = 0; r < 4; ++r) {
                    size_t idx = (size_t)(rg0 + r) * 1024 + cg;
                    C[idx] = acc[m][n][r] + resid[idx];
                }
            }
        }
    }
}

// ---------------- fused scores + softmax + PV + attn-write (stores LAST, regular) ----------------
// R12 structure with REGULAR stores (single-variable test): R12 (stores-last + NT)
// was the session-best total (509.5us) — stores still draining at s_endpgm overlap
// the next kernel — but NT stores amplified WRITE 541->763 MB (16B granules bypass
// L2 write-combining). Regular float4 stores keep the drain-overlap and restore
// the 541 MB write floor.
__global__ __launch_bounds__(256, 2)
void attn_fused(const u16* __restrict__ Qp, const u16* __restrict__ Kp,
                const void* __restrict__ maskp, const u16* __restrict__ Vt,
                float* __restrict__ attn, u16* __restrict__ ctx)
{
    const int i  = blockIdx.x;
    const int qt = (i >> 3) & 63;
    const int g  = ((i >> 9) << 3) | (i & 7);   // g%8 == i%8 -> same XCD per (b,h)
    const int h  = g & 15;
    const int b  = g >> 4;
    const int q0 = qt * 16;

    const int t = threadIdx.x;
    const int lane = t & 63;
    const int w = t >> 6;
    const int lr = lane & 15;
    const int lg = lane >> 4;

    constexpr int PLD = 1032;          // 516 dwords == 4 mod 32
    __shared__ u16 Plds[16][PLD];      // 33 KB
    __shared__ float redB[4][16];

    // mask dtype detect
    uint32_t orv = 0;
    const uint32_t* mw = (const uint32_t*)maskp;
#pragma unroll
    for (int ii = 0; ii < 64; ++ii) orv |= mw[ii];
    const bool mask_bytes = (orv > 1u);

    // Q as B-operand: q = q0+lr, k-elem = d = lg*8+i (+32)
    const u16* qb = Qp + (size_t)(b*S + q0 + lr) * DM + h*64 + lg*8;
    s16x8 qf0 = *(const s16x8*)(qb);
    s16x8 qf1 = *(const s16x8*)(qb + 32);

    const size_t mrow = (size_t)b * S * S + (size_t)(q0 + lr) * S;

    // ---- QK^T + mask + exp -> bf16 paf; also stash into Plds ----
    s16x4 paf[16];
    float hs = 0.f;
#pragma unroll
    for (int nk = 0; nk < 16; ++nk) {
        const u16* kb = Kp + (size_t)(b*S + w*256 + nk*16 + lr) * DM + h*64 + lg*8;
        s16x8 kf0 = *(const s16x8*)(kb);
        s16x8 kf1 = *(const s16x8*)(kb + 32);
        int m0, m1, m2, m3;
        {
            const size_t off = mrow + w*256 + nk*16 + lg*4;
            if (mask_bytes) {
                uchar4 mb = *(const uchar4*)((const uint8_t*)maskp + off);
                m0 = mb.x; m1 = mb.y; m2 = mb.z; m3 = mb.w;
            } else {
                int4 mi = *(const int4*)((const int*)maskp + off);
                m0 = mi.x; m1 = mi.y; m2 = mi.z; m3 = mi.w;
            }
        }
        f32x4 cc = {};
        cc = __builtin_amdgcn_mfma_f32_16x16x32_bf16(kf0, qf0, cc, 0, 0, 0);
        cc = __builtin_amdgcn_mfma_f32_16x16x32_bf16(kf1, qf1, cc, 0, 0, 0);
        cc[0] = __expf(m0 ? NEGINF : cc[0] * 0.125f);
        cc[1] = __expf(m1 ? NEGINF : cc[1] * 0.125f);
        cc[2] = __expf(m2 ? NEGINF : cc[2] * 0.125f);
        cc[3] = __expf(m3 ? NEGINF : cc[3] * 0.125f);
        hs += cc[0] + cc[1] + cc[2] + cc[3];
        s16x4 pa;
        pa[0] = (short)f2bf(cc[0]); pa[1] = (short)f2bf(cc[1]);
        pa[2] = (short)f2bf(cc[2]); pa[3] = (short)f2bf(cc[3]);
        paf[nk] = pa;
        *(s16x4*)&Plds[lr][w*256 + nk*16 + lg*4] = pa;   // raw-exp P, 8B write
    }

    // row sums (q = lr)
    hs += __shfl_xor(hs, 16, 64);
    hs += __shfl_xor(hs, 32, 64);
    if (lane < 16) redB[w][lr] = hs;
    __syncthreads();   // covers Plds writes AND redB

    const float tot = redB[0][lr] + redB[1][lr] + redB[2][lr] + redB[3][lr];
    const float inv  = tot > 0.f ? 1.0f / tot : 0.f;
    const float fill = tot > 0.f ? 0.f : (1.0f / 1024.0f);
    float invr[4];
#pragma unroll
    for (int r = 0; r < 4; ++r) {
        const int row = lg*4 + r;
        const float tr = redB[0][row] + redB[1][row] + redB[2][row] + redB[3][row];
        invr[r] = tr > 0.f ? 1.0f / tr : 0.f;
    }

    // ---- PV FIRST: wave w owns d-slice [w*16, +16), full k ----
    // A = Plds[q=lr][k=kt*32+lg*8..+8] (b128, 2-way); B = Vt row (d) contiguous 16B.
    const u16* vrow = Vt + ((size_t)g*64 + w*16 + lr) * S;
    f32x4 pacc = {};
#pragma unroll
    for (int kt = 0; kt < 32; ++kt) {
        s16x8 af = *(const s16x8*)&Plds[lr][kt*32 + lg*8];
        s16x8 vf = *(const s16x8*)(vrow + kt*32 + lg*8);
        pacc = __builtin_amdgcn_mfma_f32_16x16x32_bf16(af, vf, pacc, 0, 0, 0);
    }
    // D[col=lr -> d = w*16+lr][row=lg*4+r -> q]; scale by invr[r].
#pragma unroll
    for (int r = 0; r < 4; ++r)
        ctx[(size_t)(b*S + q0 + lg*4 + r) * DM + h*64 + w*16 + lr] = f2bf(pacc[r] * invr[r]);

    // ---- attn stores LAST (regular float4): drain overlaps kernel exit ----
    float* arow = attn + (size_t)(b*H + h) * S * S + (size_t)(q0 + lr) * S + w*256 + lg*4;
#pragma unroll
    for (int nk = 0; nk < 16; ++nk) {
        float4 st;
        st.x = fmaf(bf2f((u16)paf[nk][0]), inv, fill);
        st.y = fmaf(bf2f((u16)paf[nk][1]), inv, fill);
        st.z = fmaf(bf2f((u16)paf[nk][2]), inv, fill);
        st.w = fmaf(bf2f((u16)paf[nk][3]), inv, fill);
        *(float4*)(arow + nk*16) = st;
    }
}

// ---------------- LayerNorm over rows of 1024 ----------------
__global__ __launch_bounds__(256)
void layernorm(const float* __restrict__ x, const float* __restrict__ gamma,
               const float* __restrict__ beta, float* __restrict__ out)
{
    const int row = blockIdx.x;
    const int t = threadIdx.x;
    const float* xr = x + (size_t)row * DM;
    float4 v = *(const float4*)(xr + t*4);
    float s  = v.x + v.y + v.z + v.w;
    float s2 = v.x*v.x + v.y*v.y + v.z*v.z + v.w*v.w;
#pragma unroll
    for (int d = 1; d < 64; d <<= 1) {
        s  += __shfl_xor(s,  d, 64);
        s2 += __shfl_xor(s2, d, 64);
    }
    __shared__ float ls[4], ls2[4];
    if ((t & 63) == 0) { ls[t >> 6] = s; ls2[t >> 6] = s2; }
    __syncthreads();
    s  = ls[0] + ls[1] + ls[2] + ls[3];
    s2 = ls2[0] + ls2[1] + ls2[2] + ls2[3];
    const float mu  = s * (1.0f / DM);
    const float var = s2 * (1.0f / DM) - mu * mu;
    const float rs  = rsqrtf(var + 1e-5f);
    float4 g  = *(const float4*)(gamma + t*4);
    float4 bb = *(const float4*)(beta  + t*4);
    float4 o;
    o.x = (v.x - mu) * rs * g.x + bb.x;
    o.y = (v.y - mu) * rs * g.y + bb.y;
    o.z = (v.z - mu) * rs * g.z + bb.z;
    o.w = (v.w - mu) * rs * g.w + bb.w;
    *(float4*)(out + (size_t)row * DM + t*4) = o;
}

extern "C" void kernel_launch(void* const* d_in, const int* in_sizes, int n_in,
                              void* d_out, int out_size, void* d_ws, size_t ws_size,
                              hipStream_t stream) {
    const float* Qin  = (const float*)d_in[0];
    const float* Kin  = (const float*)d_in[1];
    const float* Vin  = (const float*)d_in[2];
    const void*  mask = d_in[3];
    const float* Wq   = (const float*)d_in[4];
    const float* Wk   = (const float*)d_in[5];
    const float* Wv   = (const float*)d_in[6];
    const float* Wfc  = (const float*)d_in[7];
    const float* gam  = (const float*)d_in[8];
    const float* bet  = (const float*)d_in[9];

    float* out  = (float*)d_out;
    float* attn = (float*)d_out + (size_t)M * DM;

    char* ws = (char*)d_ws;
    constexpr size_t SZ_X = (size_t)M * DM * 2;    // 16 MiB
    constexpr size_t SZ_W = (size_t)DM * DM * 2;   // 2 MiB
    u16* Xq  = (u16*)(ws);
    u16* Xk  = (u16*)(ws + SZ_X);
    u16* Xv  = (u16*)(ws + 2*SZ_X);
    u16* WqT = (u16*)(ws + 3*SZ_X);
    u16* WkT = (u16*)(ws + 3*SZ_X + SZ_W);
    u16* WvT = (u16*)(ws + 3*SZ_X + 2*SZ_W);
    u16* WfT = (u16*)(ws + 3*SZ_X + 3*SZ_W);
    u16* Qp  = (u16*)(ws + 3*SZ_X + 4*SZ_W);
    u16* Kp  = (u16*)(ws + 4*SZ_X + 4*SZ_W);
    u16* Vt  = (u16*)(ws + 5*SZ_X + 4*SZ_W);
    // aliases onto dead buffers:
    float* preLN = (float*)(ws);               // 32 MiB over Xq+Xk (dead after projections)
    u16*   Ctx   = (u16*)(ws + 2*SZ_X);        // 16 MiB over Xv   (dead after V projection)

    dim3 blk(256);
    cvt_all<<<dim3(M * DM / 1024, 3), blk, 0, stream>>>(Qin, Kin, Vin, Xq, Xk, Xv);
    transpose_all<<<dim3(32, 32, 4), blk, 0, stream>>>(Wq, Wk, Wv, Wfc, WqT, WkT, WvT, WfT);

    gemm_bt<0><<<dim3(64, 8), blk, 0, stream>>>(Xq, WqT, Qp, nullptr);
    gemm_bt<0><<<dim3(64, 8), blk, 0, stream>>>(Xk, WkT, Kp, nullptr);
    gemm_bt<1><<<dim3(64, 8), blk, 0, stream>>>(Xv, WvT, Vt, nullptr);

    attn_fused<<<dim3(8192), blk, 0, stream>>>(Qp, Kp, mask, Vt, attn, Ctx);

    gemm_bt<2><<<dim3(64, 8), blk, 0, stream>>>(Ctx, WfT, preLN, Qin);
    layernorm<<<dim3(M), blk, 0, stream>>>(preLN, gam, bet, out);
}

// Round 19
// 507.928 us; speedup vs baseline: 1.1614x; 1.1146x over previous
//
#include <hip/hip_runtime.h>
#include <stdint.h>

typedef unsigned short u16;
typedef float f32x4 __attribute__((ext_vector_type(4)));
typedef short s16x8 __attribute__((ext_vector_type(8)));
typedef short s16x4 __attribute__((ext_vector_type(4)));

constexpr int B  = 8;
constexpr int S  = 1024;
constexpr int DM = 1024;
constexpr int H  = 16;
constexpr int M  = B * S;          // 8192 rows
constexpr float NEGINF = -1e9f;

__device__ __forceinline__ u16 f2bf(float f) {
    union { float f; uint32_t u; } v; v.f = f;
    uint32_t u = v.u;
    uint32_t r = 0x7FFFu + ((u >> 16) & 1u);   // round-to-nearest-even
    return (u16)((u + r) >> 16);
}
__device__ __forceinline__ float bf2f(u16 h) {
    union { uint32_t u; float f; } v; v.u = ((uint32_t)h) << 16; return v.f;
}

// async global->LDS 16B (m97 form): LDS dest = wave-uniform base + lane*16
__device__ __forceinline__ void gload16(const u16* g, u16* l) {
    __builtin_amdgcn_global_load_lds(
        (const __attribute__((address_space(1))) unsigned int*)g,
        (__attribute__((address_space(3))) unsigned int*)l, 16, 0, 0);
}

// ---------------- fp32 -> bf16, all three inputs in one launch ----------------
__global__ void cvt_all(const float* __restrict__ q, const float* __restrict__ k,
                        const float* __restrict__ v,
                        u16* __restrict__ xq, u16* __restrict__ xk, u16* __restrict__ xv) {
    const float* in; u16* out;
    if (blockIdx.y == 0)      { in = q; out = xq; }
    else if (blockIdx.y == 1) { in = k; out = xk; }
    else                      { in = v; out = xv; }
    int i = (blockIdx.x * 256 + threadIdx.x) * 4;
    float4 val = *(const float4*)(in + i);
    ushort4 o;
    o.x = f2bf(val.x); o.y = f2bf(val.y); o.z = f2bf(val.z); o.w = f2bf(val.w);
    *(ushort4*)(out + i) = o;
}

// ---------------- W[k][n] fp32 -> Wt[n][k] bf16, all four weights ----------------
__global__ void transpose_all(const float* __restrict__ w0, const float* __restrict__ w1,
                              const float* __restrict__ w2, const float* __restrict__ w3,
                              u16* __restrict__ o0, u16* __restrict__ o1,
                              u16* __restrict__ o2, u16* __restrict__ o3) {
    const float* W; u16* Wt;
    switch (blockIdx.z) {
        case 0:  W = w0; Wt = o0; break;
        case 1:  W = w1; Wt = o1; break;
        case 2:  W = w2; Wt = o2; break;
        default: W = w3; Wt = o3; break;
    }
    __shared__ float tile[32][33];
    int n0 = blockIdx.x * 32, k0 = blockIdx.y * 32;
    int tx = threadIdx.x & 31, ty = threadIdx.x >> 5;   // 32 x 8
#pragma unroll
    for (int r = 0; r < 4; ++r)
        tile[ty + r*8][tx] = W[(size_t)(k0 + ty + r*8) * DM + n0 + tx];
    __syncthreads();
#pragma unroll
    for (int r = 0; r < 4; ++r)
        Wt[(size_t)(n0 + ty + r*8) * DM + k0 + tx] = f2bf(tile[tx][ty + r*8]);
}

// ---------------- GEMM: C[M x 1024] = A[M x 1024] * Bt[1024 x 1024]^T ----------------
// m97 structure: 128x128 tile, BK=32, global_load_lds width=16, linear LDS.
// Grid (m,n) = (x,y): same-m blocks share the A-band and the same id%8 -> same XCD.
// EPI 0: C bf16 row-major.  EPI 1: V transposed -> Vt[(b*16+h)*64+d][s].  EPI 2: fp32 + resid.
template<int EPI>
__global__ __launch_bounds__(256, 2)
void gemm_bt(const u16* __restrict__ A, const u16* __restrict__ Bt,
             void* __restrict__ Cv, const float* __restrict__ resid)
{
    __shared__ u16 As[128 * 32];
    __shared__ u16 Bs[128 * 32];
    const int m0 = blockIdx.x * 128;
    const int n0 = blockIdx.y * 128;
    const int t = threadIdx.x;
    const int lane = t & 63;
    const int wid = t >> 6;
    const int wm = (wid >> 1) * 64;
    const int wn = (wid & 1) * 64;
    const int lr = lane & 15;
    const int lg = lane >> 4;

    const u16* Ag = A  + (size_t)(m0 + (t >> 2)) * 1024 + (t & 3) * 8;
    const u16* Bg = Bt + (size_t)(n0 + (t >> 2)) * 1024 + (t & 3) * 8;
    u16* Al = As + t * 8;
    u16* Bl = Bs + t * 8;

    f32x4 acc[4][4] = {};

    for (int kt = 0; kt < 32; ++kt) {
        const int ko = kt * 32;
        __syncthreads();
        gload16(Ag + ko,            Al);
        gload16(Ag + 64*1024 + ko,  Al + 64*32);
        gload16(Bg + ko,            Bl);
        gload16(Bg + 64*1024 + ko,  Bl + 64*32);
        __syncthreads();
        s16x8 af[4], bfr[4];
#pragma unroll
        for (int m = 0; m < 4; ++m)
            af[m] = *(const s16x8*)(As + (wm + m*16 + lr) * 32 + lg * 8);
#pragma unroll
        for (int n = 0; n < 4; ++n)
            bfr[n] = *(const s16x8*)(Bs + (wn + n*16 + lr) * 32 + lg * 8);
#pragma unroll
        for (int m = 0; m < 4; ++m)
#pragma unroll
            for (int n = 0; n < 4; ++n)
                acc[m][n] = __builtin_amdgcn_mfma_f32_16x16x32_bf16(af[m], bfr[n], acc[m][n], 0, 0, 0);
    }

#pragma unroll
    for (int m = 0; m < 4; ++m) {
#pragma unroll
        for (int n = 0; n < 4; ++n) {
            const int rg0 = m0 + wm + m*16 + lg*4;   // D row = (lane>>4)*4 + reg
            const int cg  = n0 + wn + n*16 + lr;     // D col = lane&15
            if constexpr (EPI == 0) {
                u16* C = (u16*)Cv;
#pragma unroll
                for (int r = 0; r < 4; ++r)
                    C[(size_t)(rg0 + r) * 1024 + cg] = f2bf(acc[m][n][r]);
            } else if constexpr (EPI == 1) {
                u16* C = (u16*)Cv;
                const int bb = rg0 >> 10;
                const int s0 = rg0 & 1023;
                const int hh = cg >> 6;
                const int dd = cg & 63;
                ushort4 pk;
                pk.x = f2bf(acc[m][n][0]); pk.y = f2bf(acc[m][n][1]);
                pk.z = f2bf(acc[m][n][2]); pk.w = f2bf(acc[m][n][3]);
                *(ushort4*)(C + (size_t)((bb*16 + hh)*64 + dd) * 1024 + s0) = pk;
            } else {
                float* C = (float*)Cv;
#pragma unroll
                for (int r = 0; r < 4; ++r) {
                    size_t idx = (size_t)(rg0 + r) * 1024 + cg;
                    C[idx] = acc[m][n][r] + resid[idx];
                }
            }
        }
    }
}

// ---------------- fused scores + softmax + PV + attn-write (stores LAST, NT) ----------------
// SESSION-BEST configuration (R12, 509.5us total). Phase order: QK -> softmax ->
// PV (loads+MFMA) -> trailing NONTEMPORAL attn stores. Two measured mechanisms:
// (1) trailing stores are still draining at s_endpgm; the drain overlaps the next
// kernel's launch instead of blocking PV's vmcnt waits (R18 matrix: stores-last
// beats stores-first only with NT); (2) NT bypasses L2 -> the 537MB stream does
// not evict Ctx/weights needed by gemm_fc (regular trailing stores cost +56us,
// R18). NT's write amplification (541->763MB, 16B granules) is the lesser cost.
__global__ __launch_bounds__(256, 2)
void attn_fused(const u16* __restrict__ Qp, const u16* __restrict__ Kp,
                const void* __restrict__ maskp, const u16* __restrict__ Vt,
                float* __restrict__ attn, u16* __restrict__ ctx)
{
    const int i  = blockIdx.x;
    const int qt = (i >> 3) & 63;
    const int g  = ((i >> 9) << 3) | (i & 7);   // g%8 == i%8 -> same XCD per (b,h)
    const int h  = g & 15;
    const int b  = g >> 4;
    const int q0 = qt * 16;

    const int t = threadIdx.x;
    const int lane = t & 63;
    const int w = t >> 6;
    const int lr = lane & 15;
    const int lg = lane >> 4;

    constexpr int PLD = 1032;          // 516 dwords == 4 mod 32
    __shared__ u16 Plds[16][PLD];      // 33 KB
    __shared__ float redB[4][16];

    // mask dtype detect
    uint32_t orv = 0;
    const uint32_t* mw = (const uint32_t*)maskp;
#pragma unroll
    for (int ii = 0; ii < 64; ++ii) orv |= mw[ii];
    const bool mask_bytes = (orv > 1u);

    // Q as B-operand: q = q0+lr, k-elem = d = lg*8+i (+32)
    const u16* qb = Qp + (size_t)(b*S + q0 + lr) * DM + h*64 + lg*8;
    s16x8 qf0 = *(const s16x8*)(qb);
    s16x8 qf1 = *(const s16x8*)(qb + 32);

    const size_t mrow = (size_t)b * S * S + (size_t)(q0 + lr) * S;

    // ---- QK^T + mask + exp -> bf16 paf; also stash into Plds ----
    s16x4 paf[16];
    float hs = 0.f;
#pragma unroll
    for (int nk = 0; nk < 16; ++nk) {
        const u16* kb = Kp + (size_t)(b*S + w*256 + nk*16 + lr) * DM + h*64 + lg*8;
        s16x8 kf0 = *(const s16x8*)(kb);
        s16x8 kf1 = *(const s16x8*)(kb + 32);
        int m0, m1, m2, m3;
        {
            const size_t off = mrow + w*256 + nk*16 + lg*4;
            if (mask_bytes) {
                uchar4 mb = *(const uchar4*)((const uint8_t*)maskp + off);
                m0 = mb.x; m1 = mb.y; m2 = mb.z; m3 = mb.w;
            } else {
                int4 mi = *(const int4*)((const int*)maskp + off);
                m0 = mi.x; m1 = mi.y; m2 = mi.z; m3 = mi.w;
            }
        }
        f32x4 cc = {};
        cc = __builtin_amdgcn_mfma_f32_16x16x32_bf16(kf0, qf0, cc, 0, 0, 0);
        cc = __builtin_amdgcn_mfma_f32_16x16x32_bf16(kf1, qf1, cc, 0, 0, 0);
        cc[0] = __expf(m0 ? NEGINF : cc[0] * 0.125f);
        cc[1] = __expf(m1 ? NEGINF : cc[1] * 0.125f);
        cc[2] = __expf(m2 ? NEGINF : cc[2] * 0.125f);
        cc[3] = __expf(m3 ? NEGINF : cc[3] * 0.125f);
        hs += cc[0] + cc[1] + cc[2] + cc[3];
        s16x4 pa;
        pa[0] = (short)f2bf(cc[0]); pa[1] = (short)f2bf(cc[1]);
        pa[2] = (short)f2bf(cc[2]); pa[3] = (short)f2bf(cc[3]);
        paf[nk] = pa;
        *(s16x4*)&Plds[lr][w*256 + nk*16 + lg*4] = pa;   // raw-exp P, 8B write
    }

    // row sums (q = lr)
    hs += __shfl_xor(hs, 16, 64);
    hs += __shfl_xor(hs, 32, 64);
    if (lane < 16) redB[w][lr] = hs;
    __syncthreads();   // covers Plds writes AND redB

    const float tot = redB[0][lr] + redB[1][lr] + redB[2][lr] + redB[3][lr];
    const float inv  = tot > 0.f ? 1.0f / tot : 0.f;
    const float fill = tot > 0.f ? 0.f : (1.0f / 1024.0f);
    float invr[4];
#pragma unroll
    for (int r = 0; r < 4; ++r) {
        const int row = lg*4 + r;
        const float tr = redB[0][row] + redB[1][row] + redB[2][row] + redB[3][row];
        invr[r] = tr > 0.f ? 1.0f / tr : 0.f;
    }

    // ---- PV FIRST: wave w owns d-slice [w*16, +16), full k ----
    // A = Plds[q=lr][k=kt*32+lg*8..+8] (b128, 2-way); B = Vt row (d) contiguous 16B.
    const u16* vrow = Vt + ((size_t)g*64 + w*16 + lr) * S;
    f32x4 pacc = {};
#pragma unroll
    for (int kt = 0; kt < 32; ++kt) {
        s16x8 af = *(const s16x8*)&Plds[lr][kt*32 + lg*8];
        s16x8 vf = *(const s16x8*)(vrow + kt*32 + lg*8);
        pacc = __builtin_amdgcn_mfma_f32_16x16x32_bf16(af, vf, pacc, 0, 0, 0);
    }
    // D[col=lr -> d = w*16+lr][row=lg*4+r -> q]; scale by invr[r].
#pragma unroll
    for (int r = 0; r < 4; ++r)
        ctx[(size_t)(b*S + q0 + lg*4 + r) * DM + h*64 + w*16 + lr] = f2bf(pacc[r] * invr[r]);

    // ---- attn stores LAST (nontemporal, ext_vector f32x4) ----
    float* arow = attn + (size_t)(b*H + h) * S * S + (size_t)(q0 + lr) * S + w*256 + lg*4;
#pragma unroll
    for (int nk = 0; nk < 16; ++nk) {
        f32x4 st;
        st[0] = fmaf(bf2f((u16)paf[nk][0]), inv, fill);
        st[1] = fmaf(bf2f((u16)paf[nk][1]), inv, fill);
        st[2] = fmaf(bf2f((u16)paf[nk][2]), inv, fill);
        st[3] = fmaf(bf2f((u16)paf[nk][3]), inv, fill);
        __builtin_nontemporal_store(st, (f32x4*)(arow + nk*16));
    }
}

// ---------------- LayerNorm over rows of 1024 ----------------
__global__ __launch_bounds__(256)
void layernorm(const float* __restrict__ x, const float* __restrict__ gamma,
               const float* __restrict__ beta, float* __restrict__ out)
{
    const int row = blockIdx.x;
    const int t = threadIdx.x;
    const float* xr = x + (size_t)row * DM;
    float4 v = *(const float4*)(xr + t*4);
    float s  = v.x + v.y + v.z + v.w;
    float s2 = v.x*v.x + v.y*v.y + v.z*v.z + v.w*v.w;
#pragma unroll
    for (int d = 1; d < 64; d <<= 1) {
        s  += __shfl_xor(s,  d, 64);
        s2 += __shfl_xor(s2, d, 64);
    }
    __shared__ float ls[4], ls2[4];
    if ((t & 63) == 0) { ls[t >> 6] = s; ls2[t >> 6] = s2; }
    __syncthreads();
    s  = ls[0] + ls[1] + ls[2] + ls[3];
    s2 = ls2[0] + ls2[1] + ls2[2] + ls2[3];
    const float mu  = s * (1.0f / DM);
    const float var = s2 * (1.0f / DM) - mu * mu;
    const float rs  = rsqrtf(var + 1e-5f);
    float4 g  = *(const float4*)(gamma + t*4);
    float4 bb = *(const float4*)(beta  + t*4);
    float4 o;
    o.x = (v.x - mu) * rs * g.x + bb.x;
    o.y = (v.y - mu) * rs * g.y + bb.y;
    o.z = (v.z - mu) * rs * g.z + bb.z;
    o.w = (v.w - mu) * rs * g.w + bb.w;
    *(float4*)(out + (size_t)row * DM + t*4) = o;
}

extern "C" void kernel_launch(void* const* d_in, const int* in_sizes, int n_in,
                              void* d_out, int out_size, void* d_ws, size_t ws_size,
                              hipStream_t stream) {
    const float* Qin  = (const float*)d_in[0];
    const float* Kin  = (const float*)d_in[1];
    const float* Vin  = (const float*)d_in[2];
    const void*  mask = d_in[3];
    const float* Wq   = (const float*)d_in[4];
    const float* Wk   = (const float*)d_in[5];
    const float* Wv   = (const float*)d_in[6];
    const float* Wfc  = (const float*)d_in[7];
    const float* gam  = (const float*)d_in[8];
    const float* bet  = (const float*)d_in[9];

    float* out  = (float*)d_out;
    float* attn = (float*)d_out + (size_t)M * DM;

    char* ws = (char*)d_ws;
    constexpr size_t SZ_X = (size_t)M * DM * 2;    // 16 MiB
    constexpr size_t SZ_W = (size_t)DM * DM * 2;   // 2 MiB
    u16* Xq  = (u16*)(ws);
    u16* Xk  = (u16*)(ws + SZ_X);
    u16* Xv  = (u16*)(ws + 2*SZ_X);
    u16* WqT = (u16*)(ws + 3*SZ_X);
    u16* WkT = (u16*)(ws + 3*SZ_X + SZ_W);
    u16* WvT = (u16*)(ws + 3*SZ_X + 2*SZ_W);
    u16* WfT = (u16*)(ws + 3*SZ_X + 3*SZ_W);
    u16* Qp  = (u16*)(ws + 3*SZ_X + 4*SZ_W);
    u16* Kp  = (u16*)(ws + 4*SZ_X + 4*SZ_W);
    u16* Vt  = (u16*)(ws + 5*SZ_X + 4*SZ_W);
    // aliases onto dead buffers:
    float* preLN = (float*)(ws);               // 32 MiB over Xq+Xk (dead after projections)
    u16*   Ctx   = (u16*)(ws + 2*SZ_X);        // 16 MiB over Xv   (dead after V projection)

    dim3 blk(256);
    cvt_all<<<dim3(M * DM / 1024, 3), blk, 0, stream>>>(Qin, Kin, Vin, Xq, Xk, Xv);
    transpose_all<<<dim3(32, 32, 4), blk, 0, stream>>>(Wq, Wk, Wv, Wfc, WqT, WkT, WvT, WfT);

    gemm_bt<0><<<dim3(64, 8), blk, 0, stream>>>(Xq, WqT, Qp, nullptr);
    gemm_bt<0><<<dim3(64, 8), blk, 0, stream>>>(Xk, WkT, Kp, nullptr);
    gemm_bt<1><<<dim3(64, 8), blk, 0, stream>>>(Xv, WvT, Vt, nullptr);

    attn_fused<<<dim3(8192), blk, 0, stream>>>(Qp, Kp, mask, Vt, attn, Ctx);

    gemm_bt<2><<<dim3(64, 8), blk, 0, stream>>>(Ctx, WfT, preLN, Qin);
    layernorm<<<dim3(M), blk, 0, stream>>>(preLN, gam, bet, out);
}